// Round 1
// baseline (14014.340 us; speedup 1.0000x reference)
//
#include <hip/hip_runtime.h>
#include <math.h>

#define I_SZ 1024
#define H_SZ 1024
#define FH   4096
#define B_SZ 64
#define T_SZ 512

typedef _Float16 half8 __attribute__((ext_vector_type(8)));
typedef float    f32x4 __attribute__((ext_vector_type(4)));

// ---- workspace layout (bytes) ----
// [0,4K)      : barrier counter
// [4K, +256K) : h fp16 double buffer (2 x 64 x 1024)
// [1M, +8M)   : WhT fp16  [4096][1024]
// [16M, +8M)  : WiT fp16  [4096][1024]
// [32M, +256M): G   fp16  [32768][4096]  (pre-gates, bias fused)
#define OFF_CTRL 0
#define OFF_H16  4096
#define OFF_WHT  (1u << 20)
#define OFF_WIT  (16u << 20)
#define OFF_G    (32u << 20)

// Transpose+convert W[1024][4096] fp32 -> WT[4096][1024] fp16.
__global__ __launch_bounds__(256) void k_cvt_wT(const float* __restrict__ W,
                                                _Float16* __restrict__ WT) {
  int tid = blockIdx.x * 256 + threadIdx.x;   // 4096 n * 128 k-chunks
  int n  = tid & (FH - 1);
  int k8 = tid >> 12;                         // 0..127
  half8 h;
#pragma unroll
  for (int j = 0; j < 8; j++) h[j] = (_Float16)W[(size_t)(k8 * 8 + j) * FH + n];
  *(half8*)(WT + (size_t)n * 1024 + k8 * 8) = h;
}

// G[t*64+b][n] = x[b][t][:] @ Wi[:][n] + bi[n] + bh[n], fp16 out.
// 128x128 tile, BK=32, 4 waves of 64x64, fp16 MFMA 16x16x32.
__global__ __launch_bounds__(256) void k_gemm_pre(
    const float* __restrict__ x, const _Float16* __restrict__ WiT,
    const float* __restrict__ bi, const float* __restrict__ bh,
    _Float16* __restrict__ G) {
  __shared__ _Float16 As[128][40];  // +8 halfs pad -> 2-way LDS aliasing (free)
  __shared__ _Float16 Bs[128][40];
  const int tn = blockIdx.x, tm = blockIdx.y;   // tn fastest: tm-groups co-run
  const int tx = threadIdx.x;
  const int l = tx & 63, wv = tx >> 6;
  const int wm = wv & 1, wn = wv >> 1;
  const int r0 = tx >> 2, q0 = tx & 3;
  const int m0 = tm * 128 + r0, m1 = m0 + 64;   // M row = t*64 + b
  const float* aR0 = x + (size_t)((m0 & 63) * T_SZ + (m0 >> 6)) * I_SZ + q0 * 8;
  const float* aR1 = x + (size_t)((m1 & 63) * T_SZ + (m1 >> 6)) * I_SZ + q0 * 8;
  const _Float16* bR0 = WiT + (size_t)(tn * 128 + r0) * 1024 + q0 * 8;
  const _Float16* bR1 = WiT + (size_t)(tn * 128 + 64 + r0) * 1024 + q0 * 8;

  f32x4 acc[4][4];
#pragma unroll
  for (int a = 0; a < 4; a++)
#pragma unroll
    for (int b = 0; b < 4; b++) acc[a][b] = {0.f, 0.f, 0.f, 0.f};

  for (int kt = 0; kt < 32; kt++) {
    __syncthreads();
    float4 va0 = *(const float4*)(aR0 + kt * 32);
    float4 va1 = *(const float4*)(aR0 + kt * 32 + 4);
    float4 vb0 = *(const float4*)(aR1 + kt * 32);
    float4 vb1 = *(const float4*)(aR1 + kt * 32 + 4);
    half8 ha, hb;
    ha[0] = (_Float16)va0.x; ha[1] = (_Float16)va0.y; ha[2] = (_Float16)va0.z; ha[3] = (_Float16)va0.w;
    ha[4] = (_Float16)va1.x; ha[5] = (_Float16)va1.y; ha[6] = (_Float16)va1.z; ha[7] = (_Float16)va1.w;
    hb[0] = (_Float16)vb0.x; hb[1] = (_Float16)vb0.y; hb[2] = (_Float16)vb0.z; hb[3] = (_Float16)vb0.w;
    hb[4] = (_Float16)vb1.x; hb[5] = (_Float16)vb1.y; hb[6] = (_Float16)vb1.z; hb[7] = (_Float16)vb1.w;
    *(half8*)(&As[r0][q0 * 8])      = ha;
    *(half8*)(&As[64 + r0][q0 * 8]) = hb;
    *(half8*)(&Bs[r0][q0 * 8])      = *(const half8*)(bR0 + kt * 32);
    *(half8*)(&Bs[64 + r0][q0 * 8]) = *(const half8*)(bR1 + kt * 32);
    __syncthreads();
    half8 af[4], bf[4];
#pragma unroll
    for (int i = 0; i < 4; i++) {
      af[i] = *(const half8*)(&As[wm * 64 + i * 16 + (l & 15)][(l >> 4) * 8]);
      bf[i] = *(const half8*)(&Bs[wn * 64 + i * 16 + (l & 15)][(l >> 4) * 8]);
    }
#pragma unroll
    for (int i = 0; i < 4; i++)
#pragma unroll
      for (int j2 = 0; j2 < 4; j2++)
        acc[i][j2] = __builtin_amdgcn_mfma_f32_16x16x32_f16(af[i], bf[j2], acc[i][j2], 0, 0, 0);
  }
#pragma unroll
  for (int j2 = 0; j2 < 4; j2++) {
    const int col = tn * 128 + wn * 64 + j2 * 16 + (l & 15);
    const float bias = bi[col] + bh[col];
#pragma unroll
    for (int i = 0; i < 4; i++) {
      const int mb = tm * 128 + wm * 64 + i * 16 + ((l >> 4) << 2);
#pragma unroll
      for (int r = 0; r < 4; r++)
        G[(size_t)(mb + r) * FH + col] = (_Float16)(acc[i][j2][r] + bias);
    }
  }
}

// Persistent recurrent kernel: 256 WGs x 256 thr; WG wg owns h cols [4wg,4wg+4)
// i.e. gate cols {g*1024 + 4wg + jj}. Wh slice resident in LDS. One grid
// barrier per step; h double-buffered in global fp16.
__global__ __launch_bounds__(256) void k_lstm(
    const _Float16* __restrict__ WhT, const _Float16* __restrict__ G,
    _Float16* __restrict__ h16, float* __restrict__ out, int* ctrl) {
  __shared__ _Float16 whs[16][1032];  // [slice col c=4g+jj][k], +8 pad: 2-way only
  __shared__ float gt[4][16][17];     // per-wave 16x16 gate tile, +1 pad
  const int wg = blockIdx.x;
  const int jbase = wg * 4;
  const int tx = threadIdx.x;
  const int l = tx & 63, wv = tx >> 6;

#pragma unroll
  for (int it = 0; it < 8; it++) {    // stage Wh slice: 16 cols x 1024 k
    int chunk = tx + 256 * it;        // 0..2047 chunks of 8 halfs
    int c = chunk >> 7, k8 = chunk & 127;
    int g = c >> 2, jj = c & 3;
    *(half8*)(&whs[c][k8 * 8]) =
        *(const half8*)(WhT + (size_t)(g * 1024 + jbase + jj) * 1024 + k8 * 8);
  }
  __syncthreads();

  const int am = 16 * wv + (l & 15);        // A-frag batch row (wave owns 16 rows)
  const int kb = (l >> 4) * 8;              // A/B frag k offset within 32
  const int cc = l & 15;                    // C col = slice col
  const int cg = cc >> 2, cj = cc & 3;      // gate type / j within group
  const int mrow0 = 16 * wv + ((l >> 4) << 2);  // C rows base
  const int brow = 16 * wv + (l >> 2);      // cell-update row
  const int j = l & 3;                      // cell-update j
  const size_t gcol_c = (size_t)cg * 1024 + jbase + cj;

  float cstate = 0.f;
  float hlast = 0.f;

  for (int t = 0; t < T_SZ; t++) {
    const _Float16* hb = h16 + ((t & 1) ? 65536 : 0);
    _Float16* hn = h16 + ((t & 1) ? 0 : 65536);

    _Float16 gp[4];                          // pre-gates for C-frag positions
    const _Float16* Gt = G + (size_t)(t * 64 + mrow0) * FH + gcol_c;
#pragma unroll
    for (int r = 0; r < 4; r++) gp[r] = Gt[(size_t)r * FH];

    f32x4 acc = {0.f, 0.f, 0.f, 0.f};
    const _Float16* ap = hb + am * 1024 + kb;
    half8 af[8], bf[8];
#pragma unroll
    for (int p = 0; p < 8; p++) {
      af[p] = *(const half8*)(ap + p * 32);
      bf[p] = *(const half8*)(&whs[cc][kb + p * 32]);
    }
#pragma unroll
    for (int ki = 0; ki < 32; ki++) {       // depth-8 SW pipeline
      half8 a = af[ki & 7];
      half8 b = bf[ki & 7];
      if (ki < 24) {
        af[ki & 7] = *(const half8*)(ap + (ki + 8) * 32);
        bf[ki & 7] = *(const half8*)(&whs[cc][kb + (ki + 8) * 32]);
      }
      acc = __builtin_amdgcn_mfma_f32_16x16x32_f16(a, b, acc, 0, 0, 0);
    }

#pragma unroll
    for (int r = 0; r < 4; r++)
      gt[wv][((l >> 4) << 2) + r][cc] = acc[r] + (float)gp[r];
    __syncthreads();

    const int rl = l >> 2;
    float gi = gt[wv][rl][0 + j];
    float gf = gt[wv][rl][4 + j];
    float gg = gt[wv][rl][8 + j];
    float go = gt[wv][rl][12 + j];
    float ig = 1.f / (1.f + expf(-gi));
    float fg = 1.f / (1.f + expf(-gf));
    float gv = tanhf(gg);
    float og = 1.f / (1.f + expf(-go));
    cstate = fg * cstate + ig * gv;
    float hv = og * tanhf(cstate);
    hlast = hv;
    out[(size_t)t * (B_SZ * H_SZ) + brow * H_SZ + jbase + j] = hv;
    hn[brow * H_SZ + jbase + j] = (_Float16)hv;

    __syncthreads();
    if (t + 1 < T_SZ) {                     // monotonic grid barrier
      if (tx == 0) {
        __hip_atomic_fetch_add(ctrl, 1, __ATOMIC_ACQ_REL, __HIP_MEMORY_SCOPE_AGENT);
        const int target = (t + 1) * 256;
        while (__hip_atomic_load(ctrl, __ATOMIC_ACQUIRE, __HIP_MEMORY_SCOPE_AGENT) < target) {
          __builtin_amdgcn_s_sleep(2);
        }
      }
      __syncthreads();
    }
  }

  out[(size_t)T_SZ * (B_SZ * H_SZ) + brow * H_SZ + jbase + j] = hlast;
  out[(size_t)T_SZ * (B_SZ * H_SZ) + B_SZ * H_SZ + brow * H_SZ + jbase + j] = cstate;
}

extern "C" void kernel_launch(void* const* d_in, const int* in_sizes, int n_in,
                              void* d_out, int out_size, void* d_ws, size_t ws_size,
                              hipStream_t stream) {
  (void)in_sizes; (void)n_in; (void)out_size; (void)ws_size;
  const float* x  = (const float*)d_in[0];
  const float* Wi = (const float*)d_in[1];
  const float* Wh = (const float*)d_in[2];
  const float* bi = (const float*)d_in[3];
  const float* bh = (const float*)d_in[4];
  float* out = (float*)d_out;
  char* ws = (char*)d_ws;
  _Float16* WhT = (_Float16*)(ws + OFF_WHT);
  _Float16* WiT = (_Float16*)(ws + OFF_WIT);
  _Float16* G   = (_Float16*)(ws + OFF_G);
  _Float16* h16 = (_Float16*)(ws + OFF_H16);
  int* ctrl     = (int*)(ws + OFF_CTRL);

  // zero barrier counter + both h buffers (ws is poisoned 0xAA each call)
  hipMemsetAsync(ws, 0, OFF_H16 + 2 * B_SZ * H_SZ * sizeof(_Float16), stream);
  k_cvt_wT<<<2048, 256, 0, stream>>>(Wi, WiT);
  k_cvt_wT<<<2048, 256, 0, stream>>>(Wh, WhT);
  dim3 g2(32, 256);  // blockIdx.x = n-tile (fastest) so tm-groups share x rows
  k_gemm_pre<<<g2, 256, 0, stream>>>(x, WiT, bi, bh, G);
  k_lstm<<<256, 256, 0, stream>>>(WhT, G, h16, out, ctrl);
}

// Round 3
// 9016.400 us; speedup vs baseline: 1.5543x; 1.5543x over previous
//
#include <hip/hip_runtime.h>
#include <math.h>

#define I_SZ 1024
#define H_SZ 1024
#define FH   4096
#define B_SZ 64
#define T_SZ 512

typedef _Float16 half8 __attribute__((ext_vector_type(8)));
typedef float    f32x4 __attribute__((ext_vector_type(4)));

#define MiB (1u << 20)
#define SLOT_HALFS 65536  // 64 x 1024 fp16 h = 128 KiB per slot

// ---- ws layout (max byte = 288 MiB) ----
// [0,4K)     ctrl (barrier counter)
// [4K,+256K) h fp16 double buffer (2 slots)
// [1M,9M)    WhT fp16 [4096][1024]
// [16M,24M)  WiT fp16 [4096][1024]
// [32M,288M) G fp16 [32768][4096]

// Transpose+convert W[1024][4096] fp32 -> WT[4096][1024] fp16.
__global__ __launch_bounds__(256) void k_cvt_wT(const float* __restrict__ W,
                                                _Float16* __restrict__ WT) {
  int tid = blockIdx.x * 256 + threadIdx.x;
  int n  = tid & (FH - 1);
  int k8 = tid >> 12;
  half8 h;
#pragma unroll
  for (int j = 0; j < 8; j++) h[j] = (_Float16)W[(size_t)(k8 * 8 + j) * FH + n];
  *(half8*)(WT + (size_t)n * 1024 + k8 * 8) = h;
}

// G[t*64+b][n] = x[b][t][:] @ Wi[:][n] + bi[n] + bh[n], fp16 out. (proven r1)
__global__ __launch_bounds__(256) void k_gemm_pre(
    const float* __restrict__ x, const _Float16* __restrict__ WiT,
    const float* __restrict__ bi, const float* __restrict__ bh,
    _Float16* __restrict__ G) {
  __shared__ _Float16 As[128][40];
  __shared__ _Float16 Bs[128][40];
  const int tn = blockIdx.x, tm = blockIdx.y;
  const int tx = threadIdx.x;
  const int l = tx & 63, wv = tx >> 6;
  const int wm = wv & 1, wn = wv >> 1;
  const int r0 = tx >> 2, q0 = tx & 3;
  const int m0 = tm * 128 + r0, m1 = m0 + 64;
  const float* aR0 = x + (size_t)((m0 & 63) * T_SZ + (m0 >> 6)) * I_SZ + q0 * 8;
  const float* aR1 = x + (size_t)((m1 & 63) * T_SZ + (m1 >> 6)) * I_SZ + q0 * 8;
  const _Float16* bR0 = WiT + (size_t)(tn * 128 + r0) * 1024 + q0 * 8;
  const _Float16* bR1 = WiT + (size_t)(tn * 128 + 64 + r0) * 1024 + q0 * 8;

  f32x4 acc[4][4];
#pragma unroll
  for (int a = 0; a < 4; a++)
#pragma unroll
    for (int b = 0; b < 4; b++) acc[a][b] = {0.f, 0.f, 0.f, 0.f};

  for (int kt = 0; kt < 32; kt++) {
    __syncthreads();
    float4 va0 = *(const float4*)(aR0 + kt * 32);
    float4 va1 = *(const float4*)(aR0 + kt * 32 + 4);
    float4 vb0 = *(const float4*)(aR1 + kt * 32);
    float4 vb1 = *(const float4*)(aR1 + kt * 32 + 4);
    half8 ha, hb;
    ha[0] = (_Float16)va0.x; ha[1] = (_Float16)va0.y; ha[2] = (_Float16)va0.z; ha[3] = (_Float16)va0.w;
    ha[4] = (_Float16)va1.x; ha[5] = (_Float16)va1.y; ha[6] = (_Float16)va1.z; ha[7] = (_Float16)va1.w;
    hb[0] = (_Float16)vb0.x; hb[1] = (_Float16)vb0.y; hb[2] = (_Float16)vb0.z; hb[3] = (_Float16)vb0.w;
    hb[4] = (_Float16)vb1.x; hb[5] = (_Float16)vb1.y; hb[6] = (_Float16)vb1.z; hb[7] = (_Float16)vb1.w;
    *(half8*)(&As[r0][q0 * 8])      = ha;
    *(half8*)(&As[64 + r0][q0 * 8]) = hb;
    *(half8*)(&Bs[r0][q0 * 8])      = *(const half8*)(bR0 + kt * 32);
    *(half8*)(&Bs[64 + r0][q0 * 8]) = *(const half8*)(bR1 + kt * 32);
    __syncthreads();
    half8 af[4], bf[4];
#pragma unroll
    for (int i = 0; i < 4; i++) {
      af[i] = *(const half8*)(&As[wm * 64 + i * 16 + (l & 15)][(l >> 4) * 8]);
      bf[i] = *(const half8*)(&Bs[wn * 64 + i * 16 + (l & 15)][(l >> 4) * 8]);
    }
#pragma unroll
    for (int i = 0; i < 4; i++)
#pragma unroll
      for (int j2 = 0; j2 < 4; j2++)
        acc[i][j2] = __builtin_amdgcn_mfma_f32_16x16x32_f16(af[i], bf[j2], acc[i][j2], 0, 0, 0);
  }
#pragma unroll
  for (int j2 = 0; j2 < 4; j2++) {
    const int col = tn * 128 + wn * 64 + j2 * 16 + (l & 15);
    const float bias = bi[col] + bh[col];
#pragma unroll
    for (int i = 0; i < 4; i++) {
      const int mb = tm * 128 + wm * 64 + i * 16 + ((l >> 4) << 2);
#pragma unroll
      for (int r = 0; r < 4; r++)
        G[(size_t)(mb + r) * FH + col] = (_Float16)(acc[i][j2][r] + bias);
    }
  }
}

// Persistent recurrent kernel: 256 WGs x 256 thr; WG owns h cols [4wg,4wg+4).
// h double-buffered in global fp16; ALL h traffic via 8-byte system-scope
// relaxed atomics (sc0/sc1 bypass -> LLC-coherent, no fences, no L2
// invalidation ever). Wh/G are read-only plain cached loads (L2-resident).
__global__ __launch_bounds__(256, 1) void k_lstm(
    const _Float16* __restrict__ WhT, const _Float16* __restrict__ G,
    _Float16* __restrict__ hdb, float* __restrict__ out, int* ctrl) {
  __shared__ float gt[4][16][17];
  const int wg = blockIdx.x;
  const int jbase = wg * 4;
  const int tx = threadIdx.x;
  const int l = tx & 63, wv = tx >> 6;
  const int cc = l & 15;                    // MFMA C col / A row (l&15)
  const int cg = cc >> 2, cj = cc & 3;      // gate / col-in-slice
  const int kb = (l >> 4) * 8;              // frag k offset
  const int am = 16 * wv + cc;              // A (h) batch row
  const int mrow0 = 16 * wv + ((l >> 4) << 2);
  const int gcol = cg * 1024 + jbase + cj;
  const int lrow = l & 15;                  // cell-update local row (lanes<16)
  const int brow = 16 * wv + lrow;          // cell-update batch row

  const half8* bp = (const half8*)(WhT + (size_t)gcol * 1024 + kb);

  float cst[4] = {0.f, 0.f, 0.f, 0.f};      // 4 h-cols per lane (lanes<16 live)
  float hl[4]  = {0.f, 0.f, 0.f, 0.f};

  for (int t = 0; t < T_SZ; t++) {
    const _Float16* hb = hdb + (size_t)(t & 1) * SLOT_HALFS;
    _Float16* hn = hdb + (size_t)((t & 1) ^ 1) * SLOT_HALFS;

    _Float16 gp[4];
    const _Float16* Gt = G + (size_t)(t * 64 + mrow0) * FH + gcol;
#pragma unroll
    for (int r = 0; r < 4; r++) gp[r] = Gt[(size_t)r * FH];

    // ---- 16x16 gate tile: C[brow 16][gatecol 16] = h @ WhT-slice, K=1024 ----
    f32x4 acc = {0.f, 0.f, 0.f, 0.f};
    const unsigned long long* ap = (const unsigned long long*)(hb + am * 1024 + kb);
    unsigned long long a0[16], a1[16];
    half8 bf[16];
#pragma unroll
    for (int p = 0; p < 16; p++) {
      a0[p] = __hip_atomic_load(ap + p * 8, __ATOMIC_RELAXED, __HIP_MEMORY_SCOPE_SYSTEM);
      a1[p] = __hip_atomic_load(ap + p * 8 + 1, __ATOMIC_RELAXED, __HIP_MEMORY_SCOPE_SYSTEM);
      bf[p] = bp[p * 4];
    }
#pragma unroll
    for (int ki = 0; ki < 32; ki++) {
      union { unsigned long long u[2]; half8 h; } cv;
      cv.u[0] = a0[ki & 15]; cv.u[1] = a1[ki & 15];
      half8 b = bf[ki & 15];
      if (ki < 16) {
        a0[ki & 15] = __hip_atomic_load(ap + (ki + 16) * 8, __ATOMIC_RELAXED, __HIP_MEMORY_SCOPE_SYSTEM);
        a1[ki & 15] = __hip_atomic_load(ap + (ki + 16) * 8 + 1, __ATOMIC_RELAXED, __HIP_MEMORY_SCOPE_SYSTEM);
        bf[ki & 15] = bp[(ki + 16) * 4];
      }
      acc = __builtin_amdgcn_mfma_f32_16x16x32_f16(cv.h, b, acc, 0, 0, 0);
    }

    // gate exchange: wave-local LDS (gt[wv]), wave-synchronous, no barrier
#pragma unroll
    for (int r = 0; r < 4; r++)
      gt[wv][((l >> 4) << 2) + r][cc] = acc[r] + (float)gp[r];

    if (l < 16) {  // 16 lanes x 4 h-cols each: enables 8B-packed h store
      float hv[4];
#pragma unroll
      for (int j = 0; j < 4; j++) {
        float gi = gt[wv][lrow][0 + j];
        float gf = gt[wv][lrow][4 + j];
        float gg = gt[wv][lrow][8 + j];
        float go = gt[wv][lrow][12 + j];
        float ig = 1.f / (1.f + expf(-gi));
        float fg = 1.f / (1.f + expf(-gf));
        float gv = tanhf(gg);
        float og = 1.f / (1.f + expf(-go));
        cst[j] = fg * cst[j] + ig * gv;
        hv[j] = og * tanhf(cst[j]);
        hl[j] = hv[j];
      }
      *(float4*)(out + (size_t)t * (B_SZ * H_SZ) + brow * H_SZ + jbase) =
          make_float4(hv[0], hv[1], hv[2], hv[3]);
      union { _Float16 h[4]; unsigned long long u; } pk;
#pragma unroll
      for (int j = 0; j < 4; j++) pk.h[j] = (_Float16)hv[j];
      __hip_atomic_store((unsigned long long*)(hn + brow * H_SZ + jbase), pk.u,
                         __ATOMIC_RELAXED, __HIP_MEMORY_SCOPE_SYSTEM);
    }

    if (t + 1 < T_SZ) {
      asm volatile("s_waitcnt vmcnt(0)" ::: "memory");  // h stores at LLC
      __syncthreads();
      if (tx == 0) {
        __hip_atomic_fetch_add(ctrl, 1, __ATOMIC_RELAXED, __HIP_MEMORY_SCOPE_SYSTEM);
        const int target = (t + 1) * 256;
        int guard = 0;
        while (__hip_atomic_load(ctrl, __ATOMIC_RELAXED, __HIP_MEMORY_SCOPE_SYSTEM) < target) {
          __builtin_amdgcn_s_sleep(2);
          if (++guard > (1 << 27)) break;  // deadlock -> fast wrong-answer, not hang
        }
      }
      __syncthreads();
    }
  }

  if (l < 16) {
    const size_t ob = (size_t)T_SZ * (B_SZ * H_SZ);
    *(float4*)(out + ob + brow * H_SZ + jbase) = make_float4(hl[0], hl[1], hl[2], hl[3]);
    *(float4*)(out + ob + B_SZ * H_SZ + brow * H_SZ + jbase) =
        make_float4(cst[0], cst[1], cst[2], cst[3]);
  }
}

extern "C" void kernel_launch(void* const* d_in, const int* in_sizes, int n_in,
                              void* d_out, int out_size, void* d_ws, size_t ws_size,
                              hipStream_t stream) {
  (void)in_sizes; (void)n_in; (void)out_size; (void)ws_size;
  const float* x  = (const float*)d_in[0];
  const float* Wi = (const float*)d_in[1];
  const float* Wh = (const float*)d_in[2];
  const float* bi = (const float*)d_in[3];
  const float* bh = (const float*)d_in[4];
  float* out = (float*)d_out;
  char* ws = (char*)d_ws;

  int* ctrl     = (int*)ws;
  _Float16* hdb = (_Float16*)(ws + 4096);
  _Float16* WhT = (_Float16*)(ws + (size_t)1 * MiB);
  _Float16* WiT = (_Float16*)(ws + (size_t)16 * MiB);
  _Float16* G   = (_Float16*)(ws + (size_t)32 * MiB);

  hipMemsetAsync(ws, 0, 4096 + 2 * SLOT_HALFS * sizeof(_Float16), stream);
  k_cvt_wT<<<2048, 256, 0, stream>>>(Wi, WiT);
  k_cvt_wT<<<2048, 256, 0, stream>>>(Wh, WhT);
  dim3 g2(32, 256);
  k_gemm_pre<<<g2, 256, 0, stream>>>(x, WiT, bi, bh, G);
  k_lstm<<<256, 256, 0, stream>>>(WhT, G, hdb, out, ctrl);
}